// Round 7
// baseline (170.456 us; speedup 1.0000x reference)
//
#include <hip/hip_runtime.h>
#include <hip/hip_bf16.h>
#include <hip/hip_cooperative_groups.h>

namespace cg = cooperative_groups;

#define LN_EPS 1e-5f
#define BB 32        // batch
#define NI 200       // attended nodes
#define NIP 208      // padded to 13*16
#define DD 64        // feature dim

typedef __attribute__((ext_vector_type(8))) short bf16x8;
typedef __attribute__((ext_vector_type(4))) short bf16x4;
typedef __attribute__((ext_vector_type(4))) float f32x4;

__device__ __forceinline__ float leaky(float x) { return fmaxf(x, 0.01f * x); }
__device__ __forceinline__ short f2bf(float x) {
  __hip_bfloat16 h = __float2bfloat16(x);
  return *reinterpret_cast<short*>(&h);
}
__device__ __forceinline__ float bf2fs(short s) {
  unsigned u = ((unsigned)(unsigned short)s) << 16;
  return __uint_as_float(u);
}
__device__ __forceinline__ bf16x8 sq8(bf16x8 a) {
  bf16x8 r;
#pragma unroll
  for (int k = 0; k < 8; k++) { float f = bf2fs(a[k]); r[k] = f2bf(f * f); }
  return r;
}

// workspace layout (float offsets)
#define WS_SC 0                      // [BB][NIP][4] raw {sq1,sk1,sq2,sk2}
#define WS_T  (WS_SC + BB*NIP*4)     // [BB][2] raw iid·vi dots
#define WS_CR (WS_T + BB*2)          // [6] cred (+2 pad)
#define WS_NM (WS_CR + 8)            // ushort [BB][13312] node-major frags
#define WS_DM (WS_NM + BB*6656)      // ushort [BB][14336] d-major frags

__device__ __forceinline__ void reduce2(float& a, float& b) {
#pragma unroll
  for (int m = 1; m < 64; m <<= 1) { a += __shfl_xor(a, m, 64); b += __shfl_xor(b, m, 64); }
}
__device__ __forceinline__ void reduce4(float& a, float& b, float& c, float& d) {
#pragma unroll
  for (int m = 1; m < 64; m <<= 1) {
    a += __shfl_xor(a, m, 64); b += __shfl_xor(b, m, 64);
    c += __shfl_xor(c, m, 64); d += __shfl_xor(d, m, 64);
  }
}
__device__ __forceinline__ float reduce1(float a) {
#pragma unroll
  for (int m = 1; m < 64; m <<= 1) a += __shfl_xor(a, m, 64);
  return a;
}
__device__ __forceinline__ void rmax2(float& a, float& b) {
#pragma unroll
  for (int m = 1; m < 64; m <<= 1) {
    a = fmaxf(a, __shfl_xor(a, m, 64));
    b = fmaxf(b, __shfl_xor(b, m, 64));
  }
}

// LDS carve (69664 B total, 2 blocks/CU)
#define SM_UA   0        // short[1664*8]   26624 B node-major frags
#define SM_UAT  26624    // short[1792*8]   28672 B d-major frags
#define SM_G    55296    // short[896*8]     7168 B g A-frags
#define SM_PART 62464    // float[4][2][16]   512 B
#define SM_ST   62976    // float[NIP][6]    4992 B
#define SM_SKV  67968    // float[2][NIP]    1664 B
#define SM_WMX  69632    // float[4][2]        32 B

__global__ void __launch_bounds__(256) gat_fused(
    const float* __restrict__ emb, const float* __restrict__ lw,
    const float* __restrict__ lb, const float* __restrict__ W1,
    const float* __restrict__ W1b, const float* __restrict__ W2,
    const float* __restrict__ W2b, const float* __restrict__ a1,
    const float* __restrict__ a1b, const float* __restrict__ a2,
    const float* __restrict__ a2b, float* __restrict__ ws,
    float* __restrict__ out) {
  __shared__ __align__(16) char smem[69664];
  int tid = threadIdx.x, wv = tid >> 6, lane = tid & 63;

  // ================= phase 1: LN + ua frags + raw scores =================
  float* v_sh  = (float*)smem;          // [4][64] vq1,vk1,vq2,vk2
  float* vi_sh = (float*)smem + 256;    // [2][64] vi1,vi2

  if (wv == 0) {
    float p0 = 0, p1 = 0;
#pragma unroll 8
    for (int d = 0; d < 64; d++) {
      float x = W1[d * 64 + lane];
      p0 = fmaf(x, a1[d], p0); p1 = fmaf(x, a1[64 + d], p1);
    }
    v_sh[lane] = p0; v_sh[64 + lane] = p1;
  } else if (wv == 1) {
    float p0 = 0, p1 = 0;
#pragma unroll 8
    for (int d = 0; d < 64; d++) {
      float x = W2[d * 64 + lane];
      p0 = fmaf(x, a2[d], p0); p1 = fmaf(x, a2[64 + d], p1);
    }
    v_sh[128 + lane] = p0; v_sh[192 + lane] = p1;
  } else if (wv == 2) {
    float p0 = 0, p1 = 0;
#pragma unroll 8
    for (int d = 0; d < 64; d++) {
      p0 = fmaf(W1[d * 64 + lane], a1[128 + d], p0);
      p1 = fmaf(W2[d * 64 + lane], a2[128 + d], p1);
    }
    vi_sh[lane] = p0; vi_sh[64 + lane] = p1;
  } else if (blockIdx.x == 0) {   // wv==3, block 0: cred consts
    float c0 = reduce1(W1b[lane] * a1[lane]);
    float c1 = reduce1(W1b[lane] * a1[64 + lane]);
    float c2 = reduce1(W1b[lane] * a1[128 + lane]);
    float c3 = reduce1(W2b[lane] * a2[lane]);
    float c4 = reduce1(W2b[lane] * a2[64 + lane]);
    float c5 = reduce1(W2b[lane] * a2[128 + lane]);
    if (lane == 0) {
      ws[WS_CR + 0] = c0; ws[WS_CR + 1] = c1; ws[WS_CR + 2] = c2;
      ws[WS_CR + 3] = c3; ws[WS_CR + 4] = c4; ws[WS_CR + 5] = c5;
    }
  }
  __syncthreads();

  {
    float w = lw[lane], bi = lb[lane];
    auto lnrow = [&](int bb, int n) -> float {
      float x = emb[(size_t)(bb * 202 + n) * 64 + lane];
      float s = x, s2 = x * x;
      reduce2(s, s2);
      float mu = s * (1.f / 64);
      float var = fmaxf(s2 * (1.f / 64) - mu * mu, 0.f);
      return (x - mu) * rsqrtf(var + LN_EPS) * w + bi;
    };
    int gw = blockIdx.x * 4 + wv;
    for (int k = 0; k < 4; k++) {
      int f = gw + k * 1664;
      if (f >= BB * 202) break;
      int b = f / 202, node = f - b * 202;
      if (node == 0) continue;
      float u = lnrow(b, 0);
      float y = lnrow(b, node);
      if (node == 1) {
        out[(size_t)(b * 201) * 64 + lane] = leaky(u * y);   // ui row
        float q0 = y * vi_sh[lane], q1 = y * vi_sh[64 + lane];
        reduce2(q0, q1);
        if (lane == 0) { ws[WS_T + b * 2] = q0; ws[WS_T + b * 2 + 1] = q1; }
      } else {
        int i = node - 2, d = lane;
        float a = u * y;
        unsigned short ab = (unsigned short)f2bf(a);
        unsigned short* nm = (unsigned short*)(ws + WS_NM) + (size_t)b * 13312;
        unsigned short* dm = (unsigned short*)(ws + WS_DM) + (size_t)b * 14336;
        // node-major frag store (inverse of phase-A A/B frag load)
        nm[(((i >> 4) * 128 + (d >> 5) * 64 + ((d >> 3) & 3) * 16 + (i & 15)) << 3)
           + (d & 7)] = ab;
        // d-major frag store (inverse of phase-B B frag load)
        dm[((((i >> 5) * 4 + (d >> 4)) * 64 + ((i >> 3) & 3) * 16 + (d & 15)) << 3)
           + (i & 7)] = ab;
        float p0 = a * v_sh[lane],       p1 = a * v_sh[64 + lane];
        float p2 = a * v_sh[128 + lane], p3 = a * v_sh[192 + lane];
        reduce4(p0, p1, p2, p3);
        if (lane == 0) {
          f32x4 sc = {p0, p1, p2, p3};
          *(f32x4*)(ws + WS_SC + (size_t)(b * NIP + i) * 4) = sc;
        }
      }
    }
  }

  cg::this_grid().sync();

  // ================= phase 2: MFMA attention-value =================
  int pb = blockIdx.x & 31, jt = blockIdx.x >> 5;   // 32 batches x 13 j-tiles
  int q = lane >> 4, col = lane & 15;
  short* sUA  = (short*)(smem + SM_UA);
  short* sUAT = (short*)(smem + SM_UAT);
  short* sG   = (short*)(smem + SM_G);
  float* sPart = (float*)(smem + SM_PART);   // [wv][s][16]
  float* sST   = (float*)(smem + SM_ST);     // [i][6]
  float* skv   = (float*)(smem + SM_SKV);    // [h][NIP]
  float* wmx   = (float*)(smem + SM_WMX);    // [wv][2]

  const unsigned short* nm = (const unsigned short*)(ws + WS_NM) + (size_t)pb * 13312;
  const unsigned short* dm = (const unsigned short*)(ws + WS_DM) + (size_t)pb * 14336;
  for (int idx = tid; idx < 1664; idx += 256)
    *(bf16x8*)(sUA + idx * 8) = *(const bf16x8*)(nm + idx * 8);
  for (int idx = tid; idx < 1792; idx += 256)
    *(bf16x8*)(sUAT + idx * 8) = *(const bf16x8*)(dm + idx * 8);
  if (tid < 128) ((int*)sG)[1664 + tid] = 0;   // zero k=208..223 tail exactly

  float c0 = ws[WS_CR + 0], c1 = ws[WS_CR + 1], c2 = ws[WS_CR + 2];
  float c3 = ws[WS_CR + 3], c4 = ws[WS_CR + 4], c5 = ws[WS_CR + 5];
  float t1 = ws[WS_T + pb * 2] + c2 + a1b[0];
  float t2 = ws[WS_T + pb * 2 + 1] + c5 + a2b[0];
  float base1 = 0, base2 = 0;
  if (tid < NIP) {
    f32x4 sc = *(const f32x4*)(ws + WS_SC + (size_t)(pb * NIP + tid) * 4);
    base1 = sc.x + c0 + t1;
    base2 = sc.z + c3 + t2;
    skv[0 * NIP + tid] = sc.y + c1;   // pads: poison-finite, masked later
    skv[1 * NIP + tid] = sc.w + c4;
  }
  __syncthreads();

  float m1 = (tid < NI) ? skv[0 * NIP + tid] : -3e38f;
  float m2 = (tid < NI) ? skv[1 * NIP + tid] : -3e38f;
  rmax2(m1, m2);
  if (lane == 0) { wmx[wv * 2] = m1; wmx[wv * 2 + 1] = m2; }
  __syncthreads();

  if (tid < NIP) {
    float rm1 = 0, iv1 = 0, rm2 = 0, iv2 = 0, b1 = 0, b2 = 0;
    if (tid < NI) {
      float mx1 = fmaxf(fmaxf(wmx[0], wmx[2]), fmaxf(wmx[4], wmx[6]));
      float mx2 = fmaxf(fmaxf(wmx[1], wmx[3]), fmaxf(wmx[5], wmx[7]));
      b1 = base1; b2 = base2;
      rm1 = leaky(base1 + mx1);   // leaky monotone
      rm2 = leaky(base2 + mx2);
      float d1 = 0, d2 = 0;
#pragma unroll 4
      for (int j = 0; j < NI; j++) {
        float s1 = base1 + skv[0 * NIP + j];
        d1 += __expf(fmaxf(s1, 0.01f * s1) - rm1);
        float s2 = base2 + skv[1 * NIP + j];
        d2 += __expf(fmaxf(s2, 0.01f * s2) - rm2);
      }
      iv1 = 1.0f / d1; iv2 = 1.0f / d2;
    }
    float* st = sST + tid * 6;
    st[0] = b1; st[1] = rm1; st[2] = iv1;
    st[3] = b2; st[4] = rm2; st[5] = iv2;
  }
  __syncthreads();

  // phase A: S,T MFMAs + epilogue -> g
  bf16x8 bf0 = *(bf16x8*)(sUA + ((jt * 2 + 0) * 64 + lane) * 8);
  bf16x8 bf1 = *(bf16x8*)(sUA + ((jt * 2 + 1) * 64 + lane) * 8);
  bf16x8 b2f0 = sq8(bf0), b2f1 = sq8(bf1);
  int jglob = jt * 16 + col;
  float skj1 = skv[0 * NIP + jglob], skj2 = skv[1 * NIP + jglob];
  float mpart = 0.f, spart = 0.f;

  for (int it = wv; it < 13; it += 4) {
    bf16x8 af0 = *(bf16x8*)(sUA + ((it * 2 + 0) * 64 + lane) * 8);
    bf16x8 af1 = *(bf16x8*)(sUA + ((it * 2 + 1) * 64 + lane) * 8);
    bf16x8 a2f0 = sq8(af0), a2f1 = sq8(af1);
    f32x4 s = {0, 0, 0, 0}, t = {0, 0, 0, 0};
    s = __builtin_amdgcn_mfma_f32_16x16x32_bf16(af0, bf0, s, 0, 0, 0);
    s = __builtin_amdgcn_mfma_f32_16x16x32_bf16(af1, bf1, s, 0, 0, 0);
    t = __builtin_amdgcn_mfma_f32_16x16x32_bf16(a2f0, b2f0, t, 0, 0, 0);
    t = __builtin_amdgcn_mfma_f32_16x16x32_bf16(a2f1, b2f1, t, 0, 0, 0);
    bf16x4 gp;
#pragma unroll
    for (int r = 0; r < 4; r++) {
      int i = it * 16 + q * 4 + r;
      const float* st = sST + i * 6;
      float mu = s[r] * (1.f / 64);
      float var = fmaxf(t[r] * (1.f / 64) - mu * mu, 0.f);
      float inv = rsqrtf(var + LN_EPS);
      float sc1 = st[0] + skj1;
      float e1 = __expf(fmaxf(sc1, 0.01f * sc1) - st[1]) * st[2];
      float sc2 = st[3] + skj2;
      float e2 = __expf(fmaxf(sc2, 0.01f * sc2) - st[4]) * st[5];
      float c = 0.5f * (e1 + e2);
      float g = c * inv;
      mpart = fmaf(g, mu, mpart);
      spart += c;
      gp[r] = f2bf(g);
    }
    int kl = (it & 1) * 16 + q * 4;
    int off = ((it >> 1) * 64 + (col + 16 * (kl >> 3))) * 8 + (kl & 7);
    *(bf16x4*)(sG + off) = gp;
  }
  mpart += __shfl_xor(mpart, 16, 64); mpart += __shfl_xor(mpart, 32, 64);
  spart += __shfl_xor(spart, 16, 64); spart += __shfl_xor(spart, 32, 64);
  if (lane < 16) {
    sPart[(wv * 2 + 0) * 16 + lane] = mpart;
    sPart[(wv * 2 + 1) * 16 + lane] = spart;
  }
  __syncthreads();

  // phase B: H = G^T * UA
  f32x4 acc = {0, 0, 0, 0};
#pragma unroll
  for (int kt = 0; kt < 7; kt++) {
    bf16x8 ga = *(bf16x8*)(sG + (kt * 64 + lane) * 8);
    bf16x8 ub = *(bf16x8*)(sUAT + ((kt * 4 + wv) * 64 + lane) * 8);
    acc = __builtin_amdgcn_mfma_f32_16x16x32_bf16(ga, ub, acc, 0, 0, 0);
  }
  int d = wv * 16 + col;
  float w = lw[d], bia = lb[d];
#pragma unroll
  for (int r = 0; r < 4; r++) {
    int jl = q * 4 + r, jg = jt * 16 + jl;
    if (jg < NI) {
      float m = sPart[0 * 16 + jl] + sPart[2 * 16 + jl] +
                sPart[4 * 16 + jl] + sPart[6 * 16 + jl];
      float S = sPart[1 * 16 + jl] + sPart[3 * 16 + jl] +
                sPart[5 * 16 + jl] + sPart[7 * 16 + jl];
      // ua[jg][d] from node-major LDS frags
      int cn = jt * 128 + (d >> 5) * 64 + ((d >> 3) & 3) * 16 + (jg & 15);
      float uajd = bf2fs(sUA[cn * 8 + (d & 7)]);
      float att = w * (uajd * acc[r] - m) + bia * S;
      out[(size_t)(pb * 201 + 1 + jg) * 64 + d] = leaky(att);
    }
  }
}

extern "C" void kernel_launch(void* const* d_in, const int* in_sizes, int n_in,
                              void* d_out, int out_size, void* d_ws, size_t ws_size,
                              hipStream_t stream) {
  const float* emb = (const float*)d_in[0];
  const float* lw  = (const float*)d_in[1];
  const float* lb  = (const float*)d_in[2];
  const float* W1  = (const float*)d_in[3];
  const float* W1b = (const float*)d_in[4];
  const float* W2  = (const float*)d_in[5];
  const float* W2b = (const float*)d_in[6];
  const float* a1  = (const float*)d_in[7];
  const float* a1b = (const float*)d_in[8];
  const float* a2  = (const float*)d_in[9];
  const float* a2b = (const float*)d_in[10];
  float* ws = (float*)d_ws;
  float* out = (float*)d_out;

  void* args[] = {(void*)&emb, (void*)&lw, (void*)&lb, (void*)&W1, (void*)&W1b,
                  (void*)&W2, (void*)&W2b, (void*)&a1, (void*)&a1b, (void*)&a2,
                  (void*)&a2b, (void*)&ws, (void*)&out};
  hipLaunchCooperativeKernel((const void*)gat_fused, dim3(13 * BB), dim3(256),
                             args, 0, stream);
}

// Round 8
// 93.181 us; speedup vs baseline: 1.8293x; 1.8293x over previous
//
#include <hip/hip_runtime.h>
#include <hip/hip_bf16.h>

#define LN_EPS 1e-5f
#define BB 32        // batch
#define NI 200       // attended nodes
#define NIP 208      // padded to 13*16
#define DD 64        // feature dim

typedef __attribute__((ext_vector_type(8))) short bf16x8;
typedef __attribute__((ext_vector_type(4))) short bf16x4;
typedef __attribute__((ext_vector_type(4))) float f32x4;

__device__ __forceinline__ float leaky(float x) { return fmaxf(x, 0.01f * x); }
__device__ __forceinline__ short f2bf(float x) {
  __hip_bfloat16 h = __float2bfloat16(x);
  return *reinterpret_cast<short*>(&h);
}
__device__ __forceinline__ float bf2fs(short s) {
  unsigned u = ((unsigned)(unsigned short)s) << 16;
  return __uint_as_float(u);
}
__device__ __forceinline__ bf16x8 sq8(bf16x8 a) {
  bf16x8 r;
#pragma unroll
  for (int k = 0; k < 8; k++) { float f = bf2fs(a[k]); r[k] = f2bf(f * f); }
  return r;
}

// workspace layout (float offsets)
#define WS_SC 0                     // [BB][NIP][4] raw {sq1,sk1,sq2,sk2}
#define WS_T  (WS_SC + BB*NIP*4)    // [BB][2] raw iid·vi dots
#define WS_CR (WS_T + BB*2)         // [6] cred = Wb·a_c (+2 pad)
#define WS_UB (WS_CR + 8)           // bf16 ua [BB][NI][64] (as ushort)

__device__ __forceinline__ void reduce2(float& a, float& b) {
#pragma unroll
  for (int m = 1; m < 64; m <<= 1) { a += __shfl_xor(a, m, 64); b += __shfl_xor(b, m, 64); }
}
__device__ __forceinline__ void reduce4(float& a, float& b, float& c, float& d) {
#pragma unroll
  for (int m = 1; m < 64; m <<= 1) {
    a += __shfl_xor(a, m, 64); b += __shfl_xor(b, m, 64);
    c += __shfl_xor(c, m, 64); d += __shfl_xor(d, m, 64);
  }
}
__device__ __forceinline__ float reduce1(float a) {
#pragma unroll
  for (int m = 1; m < 64; m <<= 1) a += __shfl_xor(a, m, 64);
  return a;
}
__device__ __forceinline__ void rmax2(float& a, float& b) {
#pragma unroll
  for (int m = 1; m < 64; m <<= 1) {
    a = fmaxf(a, __shfl_xor(a, m, 64));
    b = fmaxf(b, __shfl_xor(b, m, 64));
  }
}

// kX: grid (51, BB) x 256 — unchanged from round 6 (100.7us config).
__global__ void __launch_bounds__(256) gat_kX(const float* __restrict__ emb,
                                              const float* __restrict__ lw,
                                              const float* __restrict__ lb,
                                              const float* __restrict__ W1,
                                              const float* __restrict__ W1b,
                                              const float* __restrict__ W2,
                                              const float* __restrict__ W2b,
                                              const float* __restrict__ a1,
                                              const float* __restrict__ a2,
                                              float* __restrict__ ws,
                                              float* __restrict__ out) {
  int b = blockIdx.y, tid = threadIdx.x, wv = tid >> 6, lane = tid & 63;
  int node = blockIdx.x * 4 + wv;
  __shared__ float v_sh[4][64];
  __shared__ float vi_sh[2][64];
  __shared__ float iid_sh[64];

  float w = lw[lane], bi = lb[lane];
  auto lnrow = [&](int n) -> float {
    float x = emb[(size_t)(b * 202 + n) * 64 + lane];
    float s = x, s2 = x * x;
    reduce2(s, s2);
    float mu = s * (1.f / 64);
    float var = fmaxf(s2 * (1.f / 64) - mu * mu, 0.f);
    return (x - mu) * rsqrtf(var + LN_EPS) * w + bi;
  };
  float u = lnrow(0);
  float y = 0.f;
  if (node >= 1 && node <= 201) y = lnrow(node);
  if (node == 1) {
    iid_sh[lane] = y;
    out[(size_t)(b * 201) * 64 + lane] = leaky(u * y);
  }
  if (wv == 0) {
    float p0 = 0, p1 = 0;
#pragma unroll 8
    for (int d = 0; d < 64; d++) {
      float x = W1[d * 64 + lane];
      p0 = fmaf(x, a1[d], p0); p1 = fmaf(x, a1[64 + d], p1);
    }
    v_sh[0][lane] = p0; v_sh[1][lane] = p1;
  } else if (wv == 1) {
    float p0 = 0, p1 = 0;
#pragma unroll 8
    for (int d = 0; d < 64; d++) {
      float x = W2[d * 64 + lane];
      p0 = fmaf(x, a2[d], p0); p1 = fmaf(x, a2[64 + d], p1);
    }
    v_sh[2][lane] = p0; v_sh[3][lane] = p1;
  } else if (blockIdx.x == 0 && wv == 2) {
    float p = 0;
#pragma unroll 8
    for (int d = 0; d < 64; d++) p = fmaf(W1[d * 64 + lane], a1[128 + d], p);
    vi_sh[0][lane] = p;
  } else if (blockIdx.x == 0 && wv == 3) {
    float p = 0;
#pragma unroll 8
    for (int d = 0; d < 64; d++) p = fmaf(W2[d * 64 + lane], a2[128 + d], p);
    vi_sh[1][lane] = p;
  }
  __syncthreads();

  if (node >= 2 && node <= 201) {
    int i = node - 2;
    float a = u * y;
    ((unsigned short*)(ws + WS_UB))[(size_t)(b * NI + i) * 64 + lane] =
        (unsigned short)f2bf(a);
    float p0 = a * v_sh[0][lane], p1 = a * v_sh[1][lane];
    float p2 = a * v_sh[2][lane], p3 = a * v_sh[3][lane];
    reduce4(p0, p1, p2, p3);
    if (lane == 0) {
      f32x4 sc = {p0, p1, p2, p3};
      *(f32x4*)(ws + WS_SC + (size_t)(b * NIP + i) * 4) = sc;
    }
  }
  if (blockIdx.x == 0 && wv == 0) {
    float q0 = iid_sh[lane] * vi_sh[0][lane];
    float q1 = iid_sh[lane] * vi_sh[1][lane];
    reduce2(q0, q1);
    if (lane == 0) { ws[WS_T + b * 2] = q0; ws[WS_T + b * 2 + 1] = q1; }
  }
  if (blockIdx.x == 0 && b == 0 && wv == 1) {
    float c0 = reduce1(W1b[lane] * a1[lane]);
    float c1 = reduce1(W1b[lane] * a1[64 + lane]);
    float c2 = reduce1(W1b[lane] * a1[128 + lane]);
    float c3 = reduce1(W2b[lane] * a2[lane]);
    float c4 = reduce1(W2b[lane] * a2[64 + lane]);
    float c5 = reduce1(W2b[lane] * a2[128 + lane]);
    if (lane == 0) {
      ws[WS_CR + 0] = c0; ws[WS_CR + 1] = c1; ws[WS_CR + 2] = c2;
      ws[WS_CR + 3] = c3; ws[WS_CR + 4] = c4; ws[WS_CR + 5] = c5;
    }
  }
}

// LDS carve for kY (77376 B)
#define SM_UA   0        // short[1664*8]  node-major frags
#define SM_UAT  26624    // short[1792*8]  d-major frags
#define SM_G0   55296    // short[896*8]   g frags, half 0
#define SM_G1   62464    // short[896*8]   g frags, half 1
#define SM_PART 69632    // float[2][4][2][16]
#define SM_ST   70656    // float[NIP][6]
#define SM_SKV  75648    // float[2][NIP]
#define SM_WMX  77312    // float[8][2]

// kY: grid (7, BB) x 512 (8 waves). Wave-half h processes j-tile bx*2+h;
// staging + softmax stats amortized over both tiles; 1 block/CU.
__global__ void __launch_bounds__(512) gat_kY(const float* __restrict__ ws,
                                              const float* __restrict__ lw,
                                              const float* __restrict__ lb,
                                              const float* __restrict__ a1b,
                                              const float* __restrict__ a2b,
                                              float* __restrict__ out) {
  __shared__ __align__(16) char smem[77376];
  int b = blockIdx.y, bx = blockIdx.x, tid = threadIdx.x;
  int wv = tid >> 6, lane = tid & 63, q = lane >> 4, col = lane & 15;
  int half = wv >> 2, wq = wv & 3;

  short* sUA  = (short*)(smem + SM_UA);
  short* sUAT = (short*)(smem + SM_UAT);
  short* sG0  = (short*)(smem + SM_G0);
  short* sG1  = (short*)(smem + SM_G1);
  float* sPart = (float*)(smem + SM_PART);
  float* sST   = (float*)(smem + SM_ST);
  float* skv   = (float*)(smem + SM_SKV);
  float* wmx   = (float*)(smem + SM_WMX);

  const unsigned short* uwb =
      (const unsigned short*)(ws + WS_UB) + (size_t)b * NI * 64;

  // stage node-major frags
  for (int idx = tid; idx < 1664; idx += 512) {
    int itile = idx >> 7, rem = idx & 127, kh = rem >> 6, ln = rem & 63;
    int node = itile * 16 + (ln & 15);
    int dbase = kh * 32 + (ln >> 4) * 8;
    bf16x8 pk;
    if (node < NI) pk = *(const bf16x8*)(uwb + node * 64 + dbase);
    else {
#pragma unroll
      for (int k = 0; k < 8; k++) pk[k] = 0;
    }
    *(bf16x8*)(sUA + idx * 8) = pk;
  }
  // stage d-major frags (coalesced along d)
  {
    int d = tid & 63, ir = (tid >> 6) & 3, ph = tid >> 8;
    for (int p = ph; p < 7; p += 2) {
      int i0 = p * 32 + ir * 8;
      bf16x8 pk;
#pragma unroll
      for (int u = 0; u < 8; u++)
        pk[u] = (i0 + u < NI) ? (short)uwb[(i0 + u) * 64 + d] : (short)0;
      int off = ((p * 4 + (d >> 4)) * 64 + ((d & 15) + 16 * ir)) * 8;
      *(bf16x8*)(sUAT + off) = pk;
    }
  }
  if (tid < 128) ((int*)sG0)[1664 + tid] = 0;         // zero k-tail (208..223)
  else if (tid < 256) ((int*)sG1)[1664 + (tid - 128)] = 0;

  float c0 = ws[WS_CR + 0], c1 = ws[WS_CR + 1], c2 = ws[WS_CR + 2];
  float c3 = ws[WS_CR + 3], c4 = ws[WS_CR + 4], c5 = ws[WS_CR + 5];
  float t1 = ws[WS_T + b * 2] + c2 + a1b[0];
  float t2 = ws[WS_T + b * 2 + 1] + c5 + a2b[0];
  if (tid < NIP) {
    f32x4 sc = *(const f32x4*)(ws + WS_SC + (size_t)(b * NIP + tid) * 4);
    float* st = sST + tid * 6;
    if (tid < NI) {
      st[0] = sc.x + c0 + t1;    // base1
      st[3] = sc.z + c3 + t2;    // base2
    } else { st[0] = 0; st[3] = 0; }
    st[1] = 0; st[2] = 0; st[4] = 0; st[5] = 0;
    skv[0 * NIP + tid] = sc.y + c1;   // pads poison-finite, masked below
    skv[1 * NIP + tid] = sc.w + c4;
  }
  __syncthreads();

  // block max over real j (waves 0..3 cover all j; others contribute -inf)
  float m1 = (tid < NI) ? skv[0 * NIP + tid] : -3e38f;
  float m2 = (tid < NI) ? skv[1 * NIP + tid] : -3e38f;
  rmax2(m1, m2);
  if (lane == 0) { wmx[wv * 2] = m1; wmx[wv * 2 + 1] = m2; }
  __syncthreads();

  // softmax stats: h=0 -> tid in [0,200), h=1 -> tid in [256,456)
  {
    int sh = -1, si = 0;
    if (tid < NI) { sh = 0; si = tid; }
    else if (tid >= 256 && tid < 256 + NI) { sh = 1; si = tid - 256; }
    if (sh >= 0) {
      float mx = -3e38f;
#pragma unroll
      for (int k = 0; k < 8; k++) mx = fmaxf(mx, wmx[k * 2 + sh]);
      float* st = sST + si * 6;
      float base = st[sh * 3];
      float rm = leaky(base + mx);   // leaky monotone
      const float* skh = skv + sh * NIP;
      float den = 0.f;
#pragma unroll 4
      for (int j = 0; j < NI; j++) {
        float s = base + skh[j];
        den += __expf(fmaxf(s, 0.01f * s) - rm);
      }
      st[sh * 3 + 1] = rm;
      st[sh * 3 + 2] = 1.0f / den;
    }
  }
  __syncthreads();

  // phase A: S,T MFMAs + epilogue -> g (half processes tile jt)
  int jt = bx * 2 + half;
  bool act = (jt < 13);
  short* sGh = half ? sG1 : sG0;
  float* sPh = sPart + half * 128;    // [4][2][16]
  float skj1 = 0, skj2 = 0;
  bf16x8 bf0, bf1, b2f0, b2f1;
  if (act) {
    bf0 = *(bf16x8*)(sUA + ((jt * 2 + 0) * 64 + lane) * 8);
    bf1 = *(bf16x8*)(sUA + ((jt * 2 + 1) * 64 + lane) * 8);
    b2f0 = sq8(bf0); b2f1 = sq8(bf1);
    int jglob = jt * 16 + col;
    skj1 = skv[0 * NIP + jglob]; skj2 = skv[1 * NIP + jglob];
    float mpart = 0.f, spart = 0.f;
    for (int it = wq; it < 13; it += 4) {
      bf16x8 af0 = *(bf16x8*)(sUA + ((it * 2 + 0) * 64 + lane) * 8);
      bf16x8 af1 = *(bf16x8*)(sUA + ((it * 2 + 1) * 64 + lane) * 8);
      bf16x8 a2f0 = sq8(af0), a2f1 = sq8(af1);
      f32x4 s = {0, 0, 0, 0}, t = {0, 0, 0, 0};
      s = __builtin_amdgcn_mfma_f32_16x16x32_bf16(af0, bf0, s, 0, 0, 0);
      s = __builtin_amdgcn_mfma_f32_16x16x32_bf16(af1, bf1, s, 0, 0, 0);
      t = __builtin_amdgcn_mfma_f32_16x16x32_bf16(a2f0, b2f0, t, 0, 0, 0);
      t = __builtin_amdgcn_mfma_f32_16x16x32_bf16(a2f1, b2f1, t, 0, 0, 0);
      bf16x4 gp;
#pragma unroll
      for (int r = 0; r < 4; r++) {
        int i = it * 16 + q * 4 + r;
        const float* st = sST + i * 6;
        float mu = s[r] * (1.f / 64);
        float var = fmaxf(t[r] * (1.f / 64) - mu * mu, 0.f);
        float inv = rsqrtf(var + LN_EPS);
        float sc1 = st[0] + skj1;
        float e1 = __expf(fmaxf(sc1, 0.01f * sc1) - st[1]) * st[2];
        float sc2 = st[3] + skj2;
        float e2 = __expf(fmaxf(sc2, 0.01f * sc2) - st[4]) * st[5];
        float c = 0.5f * (e1 + e2);
        float g = c * inv;
        mpart = fmaf(g, mu, mpart);
        spart += c;
        gp[r] = f2bf(g);
      }
      int kl = (it & 1) * 16 + q * 4;
      int off = ((it >> 1) * 64 + (col + 16 * (kl >> 3))) * 8 + (kl & 7);
      *(bf16x4*)(sGh + off) = gp;
    }
    mpart += __shfl_xor(mpart, 16, 64); mpart += __shfl_xor(mpart, 32, 64);
    spart += __shfl_xor(spart, 16, 64); spart += __shfl_xor(spart, 32, 64);
    if (lane < 16) {
      sPh[(wq * 2 + 0) * 16 + lane] = mpart;
      sPh[(wq * 2 + 1) * 16 + lane] = spart;
    }
  }
  __syncthreads();

  // phase B: H = G^T * UA (wave wq of the half owns d-tile wq)
  if (act) {
    f32x4 acc = {0, 0, 0, 0};
#pragma unroll
    for (int kt = 0; kt < 7; kt++) {
      bf16x8 ga = *(bf16x8*)(sGh + (kt * 64 + lane) * 8);
      bf16x8 ub = *(bf16x8*)(sUAT + ((kt * 4 + wq) * 64 + lane) * 8);
      acc = __builtin_amdgcn_mfma_f32_16x16x32_bf16(ga, ub, acc, 0, 0, 0);
    }
    int d = wq * 16 + col;
    float w = lw[d], bia = lb[d];
#pragma unroll
    for (int r = 0; r < 4; r++) {
      int jl = q * 4 + r, jg = jt * 16 + jl;
      if (jg < NI) {
        float m = sPh[0 * 16 + jl] + sPh[2 * 16 + jl] +
                  sPh[4 * 16 + jl] + sPh[6 * 16 + jl];
        float S = sPh[1 * 16 + jl] + sPh[3 * 16 + jl] +
                  sPh[5 * 16 + jl] + sPh[7 * 16 + jl];
        int cn = jt * 128 + (d >> 5) * 64 + ((d >> 3) & 3) * 16 + (jg & 15);
        float uajd = bf2fs(sUA[cn * 8 + (d & 7)]);
        float att = w * (uajd * acc[r] - m) + bia * S;
        out[(size_t)(b * 201 + 1 + jg) * 64 + d] = leaky(att);
      }
    }
  }
}

extern "C" void kernel_launch(void* const* d_in, const int* in_sizes, int n_in,
                              void* d_out, int out_size, void* d_ws, size_t ws_size,
                              hipStream_t stream) {
  const float* emb = (const float*)d_in[0];
  const float* lw  = (const float*)d_in[1];
  const float* lb  = (const float*)d_in[2];
  const float* W1  = (const float*)d_in[3];
  const float* W1b = (const float*)d_in[4];
  const float* W2  = (const float*)d_in[5];
  const float* W2b = (const float*)d_in[6];
  const float* a1  = (const float*)d_in[7];
  const float* a1b = (const float*)d_in[8];
  const float* a2  = (const float*)d_in[9];
  const float* a2b = (const float*)d_in[10];
  float* ws = (float*)d_ws;
  float* out = (float*)d_out;

  gat_kX<<<dim3(51, BB), dim3(256), 0, stream>>>(emb, lw, lb, W1, W1b, W2, W2b,
                                                 a1, a2, ws, out);
  gat_kY<<<dim3(7, BB), dim3(512), 0, stream>>>(ws, lw, lb, a1b, a2b, out);
}